// Round 6
// baseline (1663.506 us; speedup 1.0000x reference)
//
#include <hip/hip_runtime.h>

#define N_NODES 100000
#define N_EDGES 1600000
#define N_GRAPHS 64
#define HDIM 150
#define PASSES 4
#define MROWS_PAD 100032   // 1563 * 64
#define SCAN_NBLK 391      // ceil(100000/256)

typedef __attribute__((ext_vector_type(8))) short bf16x8;
typedef __attribute__((ext_vector_type(4))) float f32x4;

__device__ __forceinline__ ushort bf16_rne(float x) {
  uint u = __float_as_uint(x);
  u += 0x7FFFu + ((u >> 16) & 1u);
  return (ushort)(u >> 16);
}
__device__ __forceinline__ float bf16f(ushort h) { return __uint_as_float(((uint)h) << 16); }

// async global->LDS 16B. LDS dest = wave-uniform base + lane*16 (we pass the
// per-lane pointer matching exactly that layout, so either HW interpretation
// is identical). AS(3) cast via 32-bit truncation (CK-style, offset in low bits).
__device__ __forceinline__ void gload_lds16(const void* g, void* l) {
  __builtin_amdgcn_global_load_lds(
      (const __attribute__((address_space(1))) unsigned int*)(unsigned long long)g,
      (__attribute__((address_space(3))) unsigned int*)(unsigned int)(unsigned long long)l,
      16, 0, 0);
}

// ---------------- CSR build ----------------
__global__ void hist_kernel(const int* __restrict__ dst, int* __restrict__ counts, int n) {
  int i = blockIdx.x * blockDim.x + threadIdx.x;
  if (i < n) atomicAdd(&counts[dst[i]], 1);
}

__global__ __launch_bounds__(256) void scan1_kernel(const int* __restrict__ counts,
                                                    int* __restrict__ partials) {
  int i = blockIdx.x * 256 + threadIdx.x;
  int v = (i < N_NODES) ? counts[i] : 0;
#pragma unroll
  for (int o = 32; o; o >>= 1) v += __shfl_down(v, o);
  __shared__ int ws4[4];
  if ((threadIdx.x & 63) == 0) ws4[threadIdx.x >> 6] = v;
  __syncthreads();
  if (threadIdx.x == 0) partials[blockIdx.x] = ws4[0] + ws4[1] + ws4[2] + ws4[3];
}

__global__ __launch_bounds__(512) void scan2_kernel(int* __restrict__ partials,
                                                    int* __restrict__ row_start) {
  __shared__ int s[512];
  int t = threadIdx.x;
  int v = (t < SCAN_NBLK) ? partials[t] : 0;
  s[t] = v;
  __syncthreads();
  for (int o = 1; o < 512; o <<= 1) {
    int u = (t >= o) ? s[t - o] : 0;
    __syncthreads();
    s[t] += u;
    __syncthreads();
  }
  if (t < SCAN_NBLK) partials[t] = s[t] - v;
  if (t == 0) row_start[N_NODES] = s[511];
}

__global__ __launch_bounds__(256) void scan3_kernel(const int* __restrict__ counts,
    const int* __restrict__ partials, int* __restrict__ row_start, int* __restrict__ cursor) {
  __shared__ int s[256];
  int t = threadIdx.x, i = blockIdx.x * 256 + t;
  int v = (i < N_NODES) ? counts[i] : 0;
  s[t] = v;
  __syncthreads();
  for (int o = 1; o < 256; o <<= 1) {
    int u = (t >= o) ? s[t - o] : 0;
    __syncthreads();
    s[t] += u;
    __syncthreads();
  }
  if (i < N_NODES) {
    int ex = s[t] - v + partials[blockIdx.x];
    row_start[i] = ex; cursor[i] = ex;
  }
}

__global__ void fill_kernel(const int* __restrict__ src, const int* __restrict__ dst,
                            int* __restrict__ cursor, int* __restrict__ csr_src, int n) {
  int i = blockIdx.x * blockDim.x + threadIdx.x;
  if (i < n) {
    int pos = atomicAdd(&cursor[dst[i]], 1);
    csr_src[pos] = src[i];
  }
}

// ---------------- weight split ----------------
__global__ void wbuild_kernel(const float* __restrict__ wih, const float* __restrict__ whh,
                              ushort* __restrict__ Whi, ushort* __restrict__ Wlo) {
  int idx = blockIdx.x * 256 + threadIdx.x;
  if (idx >= 960 * 160) return;
  int n = idx / 160, k = idx - n * 160;
  int ch = n / 160, dd = n - ch * 160;
  float v = 0.f;
  if (dd < HDIM && k < HDIM)
    v = (ch < 3) ? wih[(ch * HDIM + dd) * HDIM + k] : whh[((ch - 3) * HDIM + dd) * HDIM + k];
  ushort hi = bf16_rne(v);
  ushort lo = bf16_rne(v - bf16f(hi));
  Whi[idx] = hi; Wlo[idx] = lo;
}

// ---------------- initial split: nodes fp32 -> Hhi/Hlo planes ----------------
__global__ __launch_bounds__(256) void hsplit_kernel(const float* __restrict__ h,
    ushort* __restrict__ Hhi, ushort* __restrict__ Hlo) {
  int node = blockIdx.x * 4 + (threadIdx.x >> 6);
  if (node >= N_NODES) return;
  int lane = threadIdx.x & 63;
  const float* hr = h + (size_t)node * HDIM;
  float a0 = hr[lane], a1 = hr[lane + 64];
  float a2 = (lane < 22) ? hr[lane + 128] : 0.f;
  int base = node * 160;
  ushort h0 = bf16_rne(a0), l0 = bf16_rne(a0 - bf16f(h0));
  ushort h1 = bf16_rne(a1), l1 = bf16_rne(a1 - bf16f(h1));
  Hhi[base + lane] = h0; Hlo[base + lane] = l0;
  Hhi[base + 64 + lane] = h1; Hlo[base + 64 + lane] = l1;
  if (lane < 32) {
    ushort h2 = 0, l2 = 0;
    if (lane < 22) { h2 = bf16_rne(a2); l2 = bf16_rne(a2 - bf16f(h2)); }
    Hhi[base + 128 + lane] = h2; Hlo[base + 128 + lane] = l2;
  }
}

// ---------------- segment sum from hi/lo planes -> X hi/lo planes ----------------
__global__ __launch_bounds__(256) void segsum_kernel(
    const ushort* __restrict__ Hhi, const ushort* __restrict__ Hlo,
    const int* __restrict__ row_start, const int* __restrict__ csr_src,
    ushort* __restrict__ Xhi, ushort* __restrict__ Xlo) {
  int node = blockIdx.x * 4 + (threadIdx.x >> 6);
  if (node >= N_NODES) return;
  int lane = threadIdx.x & 63;
  int b = row_start[node], e = row_start[node + 1];
  int cnt = e - b;
  float a0 = 0.f, a1 = 0.f, a2 = 0.f;
  const bool l22 = lane < 22;

  for (int base = 0; base < cnt; base += 64) {
    const int nb = min(64, cnt - base);
    int myidx = (base + lane < cnt) ? csr_src[b + base + lane] : 0;
    int jj = 0;
    for (; jj + 2 <= nb; jj += 2) {
      const int s0 = __shfl(myidx, jj);
      const int s1 = __shfl(myidx, jj + 1);
      const ushort* h0 = Hhi + (size_t)s0 * 160;
      const ushort* p0 = Hlo + (size_t)s0 * 160;
      const ushort* h1 = Hhi + (size_t)s1 * 160;
      const ushort* p1 = Hlo + (size_t)s1 * 160;
      // issue all independent loads before converting/accumulating
      ushort u0 = h0[lane],      u1 = p0[lane],      u2 = h1[lane],      u3 = p1[lane];
      ushort u4 = h0[lane + 64], u5 = p0[lane + 64], u6 = h1[lane + 64], u7 = p1[lane + 64];
      ushort v0 = 0, v1 = 0, v2 = 0, v3 = 0;
      if (l22) {
        v0 = h0[lane + 128]; v1 = p0[lane + 128];
        v2 = h1[lane + 128]; v3 = p1[lane + 128];
      }
      a0 += (bf16f(u0) + bf16f(u1)) + (bf16f(u2) + bf16f(u3));
      a1 += (bf16f(u4) + bf16f(u5)) + (bf16f(u6) + bf16f(u7));
      a2 += (bf16f(v0) + bf16f(v1)) + (bf16f(v2) + bf16f(v3));
    }
    for (; jj < nb; ++jj) {
      const int s0 = __shfl(myidx, jj);
      const ushort* h0 = Hhi + (size_t)s0 * 160;
      const ushort* p0 = Hlo + (size_t)s0 * 160;
      a0 += bf16f(h0[lane]) + bf16f(p0[lane]);
      a1 += bf16f(h0[lane + 64]) + bf16f(p0[lane + 64]);
      if (l22) a2 += bf16f(h0[lane + 128]) + bf16f(p0[lane + 128]);
    }
  }

  int basep = node * 160;
  ushort h0 = bf16_rne(a0), l0 = bf16_rne(a0 - bf16f(h0));
  ushort h1 = bf16_rne(a1), l1 = bf16_rne(a1 - bf16f(h1));
  Xhi[basep + lane] = h0; Xlo[basep + lane] = l0;
  Xhi[basep + 64 + lane] = h1; Xlo[basep + 64 + lane] = l1;
  if (lane < 32) {
    ushort h2 = 0, l2 = 0;
    if (l22) { h2 = bf16_rne(a2); l2 = bf16_rne(a2 - bf16f(h2)); }
    Xhi[basep + 128 + lane] = h2; Xlo[basep + 128 + lane] = l2;
  }
}

// ---------------- fused MFMA GRU ----------------
// All 4 A-arrays (Xhi,Xlo,Hhi,Hlo) staged via async global_load_lds (16B),
// wave w stages array w. Per-lane global address pre-permuted with the XOR
// octet swizzle so the linear LDS write (base + lane*16) lands swizzled.
// K-loop has near-zero VALU; epilogue reconstructs ho = hi+lo and writes
// next-state hi/lo planes directly.
__global__ __launch_bounds__(256) void gru_mfma_kernel(
    const ushort* __restrict__ Xhi, const ushort* __restrict__ Xlo,
    const ushort* __restrict__ Hhi, const ushort* __restrict__ Hlo,
    const ushort* __restrict__ Whi, const ushort* __restrict__ Wlo,
    const float* __restrict__ bih, const float* __restrict__ bhh,
    ushort* __restrict__ Hhi_n, ushort* __restrict__ Hlo_n) {
  __shared__ ushort smem[2][8192];  // 2 x 16KB k-buffers; f32 scratch in epilogue
  // XCD-aware swizzle (5 dblk of one mblk consecutive on the same XCD)
  const int flat = blockIdx.x;
  const int xcd = flat & 7;
  const int q = flat >> 3;           // 0..979
  const int dblk = q % 5;
  const int mblk = (q / 5) * 8 + xcd;
  if (mblk >= 1563) return;

  const int tid = threadIdx.x;
  const int w = tid >> 6;
  const int l = tid & 63;
  const int c16 = l & 15;
  const int koct = l >> 4;

  // staging source for this wave's array, per quarter qq (rows qq*16..qq*16+15)
  const ushort* srcp = (w == 0) ? Xhi : (w == 1) ? Xlo : (w == 2) ? Hhi : Hlo;
  const ushort* gq[4];
#pragma unroll
  for (int qq = 0; qq < 4; ++qq) {
    int sr = qq * 16 + (l >> 2);
    int so = (l & 3) ^ ((sr >> 1) & 3);   // inverse (=same) XOR swizzle on source
    gq[qq] = srcp + (size_t)(mblk * 64 + sr) * 160 + so * 8;
  }
  auto stage = [&](int buf, int kc) {
#pragma unroll
    for (int qq = 0; qq < 4; ++qq)
      gload_lds16(gq[qq] + kc * 32,
                  (char*)smem + buf * 16384 + w * 4096 + qq * 1024 + l * 16);
  };

  const int hi_b = (w < 2) ? 0 : 2;
  const int dt = w & 1;
  const int ch0 = (w < 2) ? 0 : 3;
  const int nbase = dblk * 32 + dt * 16 + c16;

  f32x4 acc[3][4];
#pragma unroll
  for (int a = 0; a < 3; ++a)
#pragma unroll
    for (int b = 0; b < 4; ++b) acc[a][b] = (f32x4){0.f, 0.f, 0.f, 0.f};

  stage(0, 0);
  __syncthreads();   // drains vmcnt -> buf0 ready

#pragma unroll
  for (int kc = 0; kc < 5; ++kc) {
    const int cur = kc & 1;
    if (kc < 4) stage(cur ^ 1, kc + 1);   // async, overlaps with MFMA below
    bf16x8 ahi[4], alo[4];
#pragma unroll
    for (int mt = 0; mt < 4; ++mt) {
      const int r = mt * 16 + c16;
      const int ob = (koct ^ ((r >> 1) & 3)) * 16;
      ahi[mt] = *(const bf16x8*)((char*)smem + cur * 16384 + hi_b * 4096 + r * 64 + ob);
      alo[mt] = *(const bf16x8*)((char*)smem + cur * 16384 + (hi_b + 1) * 4096 + r * 64 + ob);
    }
    bf16x8 bhi[3], blo[3];
#pragma unroll
    for (int cl = 0; cl < 3; ++cl) {
      const int wo = ((ch0 + cl) * 160 + nbase) * 160 + kc * 32 + koct * 8;
      bhi[cl] = *(const bf16x8*)(Whi + wo);
      blo[cl] = *(const bf16x8*)(Wlo + wo);
    }
#pragma unroll
    for (int cl = 0; cl < 3; ++cl)
#pragma unroll
      for (int mt = 0; mt < 4; ++mt)
        acc[cl][mt] = __builtin_amdgcn_mfma_f32_16x16x32_bf16(ahi[mt], bhi[cl], acc[cl][mt], 0, 0, 0);
#pragma unroll
    for (int cl = 0; cl < 3; ++cl)
#pragma unroll
      for (int mt = 0; mt < 4; ++mt)
        acc[cl][mt] = __builtin_amdgcn_mfma_f32_16x16x32_bf16(ahi[mt], blo[cl], acc[cl][mt], 0, 0, 0);
#pragma unroll
    for (int cl = 0; cl < 3; ++cl)
#pragma unroll
      for (int mt = 0; mt < 4; ++mt)
        acc[cl][mt] = __builtin_amdgcn_mfma_f32_16x16x32_bf16(alo[mt], bhi[cl], acc[cl][mt], 0, 0, 0);
    __syncthreads();   // drains the async stage for buf^1 + releases buf
  }

  // epilogue: H-waves publish via LDS; X-waves combine + write hi/lo planes
  float* eps = (float*)smem;
  if (w >= 2) {
    const int wi = w - 2;
#pragma unroll
    for (int cl = 0; cl < 3; ++cl)
#pragma unroll
      for (int mt = 0; mt < 4; ++mt)
        *(f32x4*)&eps[(((wi * 3 + cl) * 4 + mt) * 64 + l) * 4] = acc[cl][mt];
  }
  __syncthreads();
  if (w < 2) {
    const int d = dblk * 32 + dt * 16 + c16;
    if (d < HDIM) {
      const float bir = bih[d], biz = bih[HDIM + d], bin = bih[2 * HDIM + d];
      const float bhr = bhh[d], bhz = bhh[HDIM + d], bhn = bhh[2 * HDIM + d];
#pragma unroll
      for (int mt = 0; mt < 4; ++mt) {
        const int mb = mblk * 64 + mt * 16 + koct * 4;
        f32x4 hr4 = *(const f32x4*)&eps[(((dt * 3 + 0) * 4 + mt) * 64 + l) * 4];
        f32x4 hz4 = *(const f32x4*)&eps[(((dt * 3 + 1) * 4 + mt) * 64 + l) * 4];
        f32x4 hn4 = *(const f32x4*)&eps[(((dt * 3 + 2) * 4 + mt) * 64 + l) * 4];
#pragma unroll
        for (int j = 0; j < 4; ++j) {
          const int m = mb + j;
          if (m < N_NODES) {
            const size_t o = (size_t)m * 160 + d;
            const float ho = bf16f(Hhi[o]) + bf16f(Hlo[o]);
            const float r = 1.f / (1.f + __expf(-(acc[0][mt][j] + bir + hr4[j] + bhr)));
            const float z = 1.f / (1.f + __expf(-(acc[1][mt][j] + biz + hz4[j] + bhz)));
            const float na = acc[2][mt][j] + bin + r * (hn4[j] + bhn);
            const float nn = 1.f - 2.f / (__expf(2.f * na) + 1.f);  // tanh
            const float hv = (1.f - z) * nn + z * ho;
            const ushort hh = bf16_rne(hv);
            Hhi_n[o] = hh;
            Hlo_n[o] = bf16_rne(hv - bf16f(hh));
          }
        }
      }
    }
  }
}

// ---------------- readout ----------------
__global__ __launch_bounds__(64) void graph_accum_kernel(
    const ushort* __restrict__ Hhi, const ushort* __restrict__ Hlo,
    const int* __restrict__ gids, float* __restrict__ gacc) {
  const int lane = threadIdx.x;
  const int nb = gridDim.x;
  int chunk = (N_NODES + nb - 1) / nb;
  int b = blockIdx.x * chunk, e = min(b + chunk, N_NODES);
  if (b >= e) return;
  float a0 = 0.f, a1 = 0.f, a2 = 0.f;
  int cur = gids[b];
  for (int i = b; i < e; ++i) {
    int gid = gids[i];
    if (gid != cur) {
      atomicAdd(&gacc[cur * HDIM + lane], a0);
      atomicAdd(&gacc[cur * HDIM + lane + 64], a1);
      if (lane < 22) atomicAdd(&gacc[cur * HDIM + lane + 128], a2);
      a0 = a1 = a2 = 0.f; cur = gid;
    }
    const ushort* rh = Hhi + (size_t)i * 160;
    const ushort* rl = Hlo + (size_t)i * 160;
    a0 += bf16f(rh[lane]) + bf16f(rl[lane]);
    a1 += bf16f(rh[lane + 64]) + bf16f(rl[lane + 64]);
    if (lane < 22) a2 += bf16f(rh[lane + 128]) + bf16f(rl[lane + 128]);
  }
  atomicAdd(&gacc[cur * HDIM + lane], a0);
  atomicAdd(&gacc[cur * HDIM + lane + 64], a1);
  if (lane < 22) atomicAdd(&gacc[cur * HDIM + lane + 128], a2);
}

__global__ __launch_bounds__(192) void readout_kernel(const float* __restrict__ gacc,
    const float* __restrict__ fc1w, const float* __restrict__ fc1b,
    const float* __restrict__ fc2w, const float* __restrict__ fc2b,
    const float* __restrict__ fclw, const float* __restrict__ fclb,
    float* __restrict__ out) {
  __shared__ float x0[HDIM];
  __shared__ float y1[80];
  __shared__ float y2[80];
  int g = blockIdx.x, t = threadIdx.x;
  if (t < HDIM) {
    float v = logf(gacc[g * HDIM + t]);
    if (v != v) v = 0.f;
    x0[t] = fmaxf(v, 0.f);
  }
  __syncthreads();
  if (t < 80) {
    float s = fc1b[t];
    for (int k = 0; k < HDIM; ++k) s += x0[k] * fc1w[t * HDIM + k];
    y1[t] = (s > 0.f) ? s : 0.01f * s;
  }
  __syncthreads();
  if (t < 80) {
    float s = fc2b[t];
    for (int k = 0; k < 80; ++k) s += y1[k] * fc2w[t * 80 + k];
    y2[t] = (s > 0.f) ? s : 0.01f * s;
  }
  __syncthreads();
  if (t < 10) {
    float s = fclb[t];
    for (int k = 0; k < 80; ++k) s += y2[k] * fclw[t * 80 + k];
    out[g * 10 + t] = s;
  }
}

// ---------------- launch ----------------
extern "C" void kernel_launch(void* const* d_in, const int* in_sizes, int n_in,
                              void* d_out, int out_size, void* d_ws, size_t ws_size,
                              hipStream_t stream) {
  const float* nodes = (const float*)d_in[0];
  const int* src = (const int*)d_in[1];
  const int* dst = (const int*)d_in[2];
  const int* gids = (const int*)d_in[3];
  const float* wih = (const float*)d_in[4];
  const float* whh = (const float*)d_in[5];
  const float* bih = (const float*)d_in[6];
  const float* bhh = (const float*)d_in[7];
  const float* fc1w = (const float*)d_in[8];
  const float* fc1b = (const float*)d_in[9];
  const float* fc2w = (const float*)d_in[10];
  const float* fc2b = (const float*)d_in[11];
  const float* fclw = (const float*)d_in[12];
  const float* fclb = (const float*)d_in[13];
  float* out = (float*)d_out;

  char* wsp = (char*)d_ws;
  size_t off = 0;
  auto carve = [&](size_t bytes) {
    void* p = wsp + off;
    off += (bytes + 255) & ~(size_t)255;
    return p;
  };
  int* counts   = (int*)carve((size_t)N_NODES * 4);
  int* rowstart = (int*)carve((size_t)(N_NODES + 1) * 4);
  int* cursor   = (int*)carve((size_t)N_NODES * 4);
  int* partials = (int*)carve((size_t)512 * 4);
  int* csr      = (int*)carve((size_t)N_EDGES * 4);
  ushort* Xhi   = (ushort*)carve((size_t)MROWS_PAD * 160 * 2);
  ushort* Xlo   = (ushort*)carve((size_t)MROWS_PAD * 160 * 2);
  ushort* HhiA  = (ushort*)carve((size_t)MROWS_PAD * 160 * 2);
  ushort* HloA  = (ushort*)carve((size_t)MROWS_PAD * 160 * 2);
  ushort* HhiB  = (ushort*)carve((size_t)MROWS_PAD * 160 * 2);
  ushort* HloB  = (ushort*)carve((size_t)MROWS_PAD * 160 * 2);
  ushort* Whi   = (ushort*)carve((size_t)960 * 160 * 2);
  ushort* Wlo   = (ushort*)carve((size_t)960 * 160 * 2);
  float* gacc   = (float*)carve((size_t)N_GRAPHS * HDIM * 4);
  (void)ws_size; (void)in_sizes; (void)n_in; (void)out_size;

  hipMemsetAsync(counts, 0, (size_t)N_NODES * 4, stream);
  hipMemsetAsync(gacc, 0, (size_t)N_GRAPHS * HDIM * 4, stream);

  hist_kernel<<<(N_EDGES + 255) / 256, 256, 0, stream>>>(dst, counts, N_EDGES);
  scan1_kernel<<<SCAN_NBLK, 256, 0, stream>>>(counts, partials);
  scan2_kernel<<<1, 512, 0, stream>>>(partials, rowstart);
  scan3_kernel<<<SCAN_NBLK, 256, 0, stream>>>(counts, partials, rowstart, cursor);
  fill_kernel<<<(N_EDGES + 255) / 256, 256, 0, stream>>>(src, dst, cursor, csr, N_EDGES);
  wbuild_kernel<<<600, 256, 0, stream>>>(wih, whh, Whi, Wlo);
  hsplit_kernel<<<25000, 256, 0, stream>>>(nodes, HhiA, HloA);

  const ushort* curHi = HhiA; const ushort* curLo = HloA;
  ushort* nxtHi = HhiB; ushort* nxtLo = HloB;
  for (int p = 0; p < PASSES; ++p) {
    segsum_kernel<<<25000, 256, 0, stream>>>(curHi, curLo, rowstart, csr, Xhi, Xlo);
    gru_mfma_kernel<<<7840, 256, 0, stream>>>(
        Xhi, Xlo, curHi, curLo, Whi, Wlo, bih, bhh, nxtHi, nxtLo);
    const ushort* th = curHi; const ushort* tl = curLo;
    curHi = nxtHi; curLo = nxtLo;
    nxtHi = (ushort*)th; nxtLo = (ushort*)tl;
  }

  graph_accum_kernel<<<512, 64, 0, stream>>>(curHi, curLo, gids, gacc);
  readout_kernel<<<N_GRAPHS, 192, 0, stream>>>(gacc, fc1w, fc1b, fc2w, fc2b, fclw, fclb, out);
}